// Round 8
// baseline (155.327 us; speedup 1.0000x reference)
//
#include <hip/hip_runtime.h>

#define BB 64
#define KK 16
#define LL 16384
#define NROW (BB * KK)   // 1024 rows
#define SEGS 4
#define SEGEL (LL / SEGS)    // 4096 elements per K1 block
#define CAP 512              // per-row raw candidate capacity (global lists)

// monotone float->uint key so atomicMax(uint) orders like float; 0 < key(x) forall x
__device__ __forceinline__ unsigned fkey(float f) {
  unsigned u = __float_as_uint(f);
  return (u & 0x80000000u) ? ~u : (u | 0x80000000u);
}
__device__ __forceinline__ float funkey(unsigned k) {
  unsigned u = (k & 0x80000000u) ? (k & 0x7fffffffu) : ~k;
  return __uint_as_float(u);
}

// ---------------------------------------------------------------------------
// K1: THE ONLY FULL PASS.  Fill-shaped: 4 KB/block, no LDS row, no serial
// tail.  Each block: segment max -> atomicMax(rowmax[row]); collect
// candidates {z > segmax-1} into per-row global lists.  Since segmax <=
// rowmax, this is a superset of the true candidate set {z > rowmax-1}
// (~14/block vs ~10); K2 re-filters with the true threshold.
// Blocks [NROW*SEGS, +BB) do per-batch mask stats (fused, same pass).
// ---------------------------------------------------------------------------
__global__ __launch_bounds__(256) void k1_pass(
    const float* __restrict__ logits, const float* __restrict__ mask,
    unsigned* __restrict__ rowmax, int* __restrict__ cnt,
    float* __restrict__ cval, int* __restrict__ cidx,
    float* __restrict__ stats) {
  int gb = blockIdx.x, t = threadIdx.x, wave = t >> 6, lane = t & 63;
  __shared__ float l0[4], l1[4];
  if (gb < NROW * SEGS) {
    int row = gb >> 2, seg = gb & 3;
    const float4* zv =
        reinterpret_cast<const float4*>(logits + (size_t)row * LL + seg * SEGEL);
    float4 v0 = zv[t], v1 = zv[t + 256], v2 = zv[t + 512], v3 = zv[t + 768];
    float m0 = fmaxf(fmaxf(v0.x, v0.y), fmaxf(v0.z, v0.w));
    float m1 = fmaxf(fmaxf(v1.x, v1.y), fmaxf(v1.z, v1.w));
    float m2 = fmaxf(fmaxf(v2.x, v2.y), fmaxf(v2.z, v2.w));
    float m3 = fmaxf(fmaxf(v3.x, v3.y), fmaxf(v3.z, v3.w));
    float mx = fmaxf(fmaxf(m0, m1), fmaxf(m2, m3));
    for (int off = 32; off; off >>= 1) mx = fmaxf(mx, __shfl_xor(mx, off));
    if (lane == 0) l0[wave] = mx;
    __syncthreads();
    float bmax = fmaxf(fmaxf(l0[0], l0[1]), fmaxf(l0[2], l0[3]));
    float thr = bmax - 1.0f;
    // filter & append (values held in 16 VGPRs across the barrier)
    float vv[16] = {v0.x, v0.y, v0.z, v0.w, v1.x, v1.y, v1.z, v1.w,
                    v2.x, v2.y, v2.z, v2.w, v3.x, v3.y, v3.z, v3.w};
    float* cv = cval + (size_t)row * CAP;
    int*   ci = cidx + (size_t)row * CAP;
#pragma unroll
    for (int c = 0; c < 4; ++c) {
#pragma unroll
      for (int e = 0; e < 4; ++e) {
        float x = vv[c * 4 + e];
        if (x > thr) {
          int pos = atomicAdd(&cnt[row], 1);
          if (pos < CAP) {
            cv[pos] = x;
            ci[pos] = seg * SEGEL + c * 1024 + t * 4 + e;
          }
        }
      }
    }
    if (t == 0) atomicMax(&rowmax[row], fkey(bmax));
  } else {
    int b = gb - NROW * SEGS;
    const float* m = mask + (size_t)b * LL;
    float s = 0.f, sq = 0.f;
#pragma unroll
    for (int j = 0; j < 16; ++j) {
      float4 v = reinterpret_cast<const float4*>(m)[j * 256 + t];
      s  += v.x + v.y + v.z + v.w;
      sq += v.x * v.x + v.y * v.y + v.z * v.z + v.w * v.w;
    }
    for (int off = 32; off; off >>= 1) {
      s += __shfl_xor(s, off); sq += __shfl_xor(sq, off);
    }
    if (lane == 0) { l0[wave] = s; l1[wave] = sq; }
    __syncthreads();
    if (t == 0) {
      float S  = l0[0] + l0[1] + l0[2] + l0[3];
      float SQ = l1[0] + l1[1] + l1[2] + l1[3];
      float inv = 1.0f / fmaxf(S, 1e-12f);
      stats[2 * b]     = inv;
      stats[2 * b + 1] = SQ * inv * inv;
    }
  }
}

// ---------------------------------------------------------------------------
// K2: one wave per row.  Re-filter raw candidates against the TRUE
// threshold rowmax-1, compact into this wave's LDS slice, then:
//   n <= 64 : bitonic sort + the reference's exact support test
//   n <= 512: tau bisection over the LDS list (exact tau from support)
//   overflow: full-row bisection from global (correctness only)
// Loss = sum p^2 - 2 sum pq + sum q^2; first two terms candidate-only.
// ---------------------------------------------------------------------------
__global__ __launch_bounds__(256) void k2_solve(
    const float* __restrict__ logits, const float* __restrict__ mask,
    const unsigned* __restrict__ rowmax, const int* __restrict__ cnt,
    const float* __restrict__ cval, const int* __restrict__ cidx,
    const float* __restrict__ stats, float* __restrict__ part) {
  int t = threadIdx.x, wave = t >> 6, lane = t & 63;
  int row = blockIdx.x * 4 + wave;
  int b = row >> 4;
  __shared__ float cv[4][CAP];
  __shared__ int   ci[4][CAP];
  __shared__ int   wn[4];
  if (lane == 0) wn[wave] = 0;
  // (no __syncthreads needed: each wave touches only its own LDS slice;
  //  within-wave DS ordering is by lgkmcnt)
  int nraw = cnt[row];
  bool ovf = nraw > CAP;
  float zmax = funkey(rowmax[row]);
  float thr = zmax - 1.0f;
  float inv_s = stats[2 * b], sumq2 = stats[2 * b + 1];
  const float scale = 0.5f / (float)(BB * KK);
  const float* m = mask + (size_t)b * LL;
  const float* gv = cval + (size_t)row * CAP;
  const int*   gi = cidx + (size_t)row * CAP;
  float a1 = 0.f, a2 = 0.f;

  if (!ovf) {
    // re-filter with true threshold into LDS
    for (int i0 = 0; i0 < nraw; i0 += 64) {
      int i = i0 + lane;
      if (i < nraw) {
        float x = gv[i];
        if (x > thr) {
          int p = atomicAdd(&wn[wave], 1);
          cv[wave][p] = x;
          ci[wave][p] = gi[i];
        }
      }
    }
    int n = wn[wave];   // all prior wave DS ops drained by lgkmcnt before read
    if (n <= 64) {
      float c = (lane < n) ? cv[wave][lane] : -3.0e38f;
#pragma unroll
      for (int size = 2; size <= 64; size <<= 1) {
#pragma unroll
        for (int stride = size >> 1; stride > 0; stride >>= 1) {
          float other = __shfl_xor(c, stride);
          bool dirDesc = ((lane & size) == 0);
          bool takeMax = (dirDesc == ((lane & stride) == 0));
          c = takeMax ? fmaxf(c, other) : fminf(c, other);
        }
      }
      float cum = c;
#pragma unroll
      for (int off = 1; off < 64; off <<= 1) {
        float y = __shfl_up(cum, off);
        if (lane >= off) cum += y;
      }
      bool sup = (lane < n) && (1.0f + (float)(lane + 1) * c > cum);
      unsigned long long bal = __ballot(sup);
      int k = __popcll(bal);              // >= 1 (row max always qualifies)
      float S = sup ? c : 0.f;
      for (int off = 32; off; off >>= 1) S += __shfl_xor(S, off);
      float tau = (S - 1.0f) / (float)k;
      if (lane < n) {
        float p = fmaxf(cv[wave][lane] - tau, 0.f);
        if (p > 0.f) { float q = m[ci[wave][lane]] * inv_s; a1 = p * p; a2 = p * q; }
      }
    } else {
      int nj = (n + 63) >> 6;
      float lo = thr, hi = zmax;
      for (int it = 0; it < 30; ++it) {
        float mid = 0.5f * (lo + hi), s = 0.f;
        for (int j = 0; j < nj; ++j) {
          int i = j * 64 + lane;
          float cc = (i < n) ? cv[wave][i] : -3.0e38f;
          s += fmaxf(cc - mid, 0.f);
        }
        for (int off = 32; off; off >>= 1) s += __shfl_xor(s, off);
        if (s >= 1.0f) lo = mid; else hi = mid;
      }
      float S = 0.f, kc = 0.f;
      for (int j = 0; j < nj; ++j) {
        int i = j * 64 + lane;
        float cc = (i < n) ? cv[wave][i] : -3.0e38f;
        if (cc > lo) { S += cc; kc += 1.f; }
      }
      for (int off = 32; off; off >>= 1) {
        S += __shfl_xor(S, off); kc += __shfl_xor(kc, off);
      }
      float tau = (S - 1.0f) / kc;
      for (int j = 0; j < nj; ++j) {
        int i = j * 64 + lane;
        if (i < n) {
          float p = fmaxf(cv[wave][i] - tau, 0.f);
          if (p > 0.f) { float q = m[ci[wave][i]] * inv_s; a1 += p * p; a2 += p * q; }
        }
      }
    }
  } else {
    // overflow fallback: whole row from global, one wave (correctness only)
    const float* z = logits + (size_t)row * LL;
    float lo = thr, hi = zmax;
    for (int it = 0; it < 30; ++it) {
      float mid = 0.5f * (lo + hi), s = 0.f;
      for (int i = lane; i < LL; i += 64) s += fmaxf(z[i] - mid, 0.f);
      for (int off = 32; off; off >>= 1) s += __shfl_xor(s, off);
      if (s >= 1.0f) lo = mid; else hi = mid;
    }
    float S = 0.f, kc = 0.f;
    for (int i = lane; i < LL; i += 64) {
      float zi = z[i];
      if (zi > lo) { S += zi; kc += 1.f; }
    }
    for (int off = 32; off; off >>= 1) {
      S += __shfl_xor(S, off); kc += __shfl_xor(kc, off);
    }
    float tau = (S - 1.0f) / kc;
    for (int i = lane; i < LL; i += 64) {
      float p = fmaxf(z[i] - tau, 0.f);
      if (p > 0.f) { float q = m[i] * inv_s; a1 += p * p; a2 += p * q; }
    }
  }

  for (int off = 32; off; off >>= 1) {
    a1 += __shfl_xor(a1, off); a2 += __shfl_xor(a2, off);
  }
  if (lane == 0) part[row] = (a1 - 2.f * a2 + sumq2) * scale;
}

// ---------------------------------------------------------------------------
// K3: single-block final reduction of the 1024 per-row losses.
// ---------------------------------------------------------------------------
__global__ __launch_bounds__(256) void k3_reduce(
    const float* __restrict__ part, float* __restrict__ out) {
  int t = threadIdx.x;
  float s = 0.f;
#pragma unroll
  for (int j = 0; j < NROW / 256; ++j) s += part[j * 256 + t];
  for (int off = 32; off; off >>= 1) s += __shfl_xor(s, off);
  __shared__ float ls[4];
  if ((t & 63) == 0) ls[t >> 6] = s;
  __syncthreads();
  if (t == 0) out[0] = ls[0] + ls[1] + ls[2] + ls[3];
}

extern "C" void kernel_launch(void* const* d_in, const int* in_sizes, int n_in,
                              void* d_out, int out_size, void* d_ws, size_t ws_size,
                              hipStream_t stream) {
  const float* logits = (const float*)d_in[0];  // (B,K,L) fp32
  const float* mask   = (const float*)d_in[1];  // (B,L)   fp32
  char* ws = (char*)d_ws;
  // ws: [0,512) stats | [512,4608) rowmax | [4608,8704) cnt |
  //     [8704,12800) part | [16384,+2MB) cval | +2MB cidx
  float*    stats  = (float*)ws;
  unsigned* rowmax = (unsigned*)(ws + 512);
  int*      cnt    = (int*)(ws + 4608);
  float*    part   = (float*)(ws + 8704);
  float*    cval   = (float*)(ws + 16384);
  int*      cidx   = (int*)(ws + 16384 + (size_t)NROW * CAP * 4);
  float* out = (float*)d_out;

  hipMemsetAsync(ws + 512, 0, 8192, stream);  // rowmax keys + cnt
  k1_pass<<<NROW * SEGS + BB, 256, 0, stream>>>(logits, mask, rowmax, cnt,
                                                cval, cidx, stats);
  k2_solve<<<NROW / 4, 256, 0, stream>>>(logits, mask, rowmax, cnt, cval,
                                         cidx, stats, part);
  k3_reduce<<<1, 256, 0, stream>>>(part, out);
}

// Round 9
// 125.851 us; speedup vs baseline: 1.2342x; 1.2342x over previous
//
#include <hip/hip_runtime.h>

#define BB 64
#define KK 16
#define LL 16384
#define NROW (BB * KK)   // 1024 rows
#define THR0 2.0f        // speculative filter threshold (see header comment)
#define CAPL 768         // LDS speculative candidate capacity (E[n]=373, sd 19)

// ---------------------------------------------------------------------------
// fused_rows: blocks [0,NROW) handle one sparsemax row each; blocks
// [NROW,NROW+BB) compute per-batch mask stats (no cross-block reads, so
// fusing into one dispatch is safe).
//
// KEY STRUCTURAL CHANGE vs R2-R8: the candidate filter no longer waits for
// the row max.  Each element is compared against the FIXED threshold
// THR0=2.0 in the same instruction stream as the load (no barrier between
// load and use).  For N(0,1) rows at L=16384, P(zmax < 3.0) ~ e^-22, so
// {z > 2.0} superset-covers the true candidate set {z > zmax-1} essentially
// always; a post-hoc check (thr >= THR0) guards correctness, falling back
// to a full-row bisection for adversarial inputs.
// Per-row outputs: p1[row] = sum p^2, p2[row] = sum p*mask (raw, unscaled)
// so the final reduce applies inv_s/sumq2 (lets mask-stats live in the same
// dispatch).
// ---------------------------------------------------------------------------
__global__ __launch_bounds__(256) void fused_rows(
    const float* __restrict__ logits, const float* __restrict__ mask,
    float* __restrict__ stats, float* __restrict__ p1, float* __restrict__ p2) {
  int gb = blockIdx.x, t = threadIdx.x, wave = t >> 6, lane = t & 63;
  __shared__ float l0[4], l1[4];

  if (gb >= NROW) {
    // ---- mask stats for batch b ----
    int b = gb - NROW;
    const float* m = mask + (size_t)b * LL;
    float s = 0.f, sq = 0.f;
#pragma unroll
    for (int j = 0; j < 16; ++j) {
      float4 v = reinterpret_cast<const float4*>(m)[j * 256 + t];
      s  += v.x + v.y + v.z + v.w;
      sq += v.x * v.x + v.y * v.y + v.z * v.z + v.w * v.w;
    }
    for (int off = 32; off; off >>= 1) {
      s += __shfl_xor(s, off); sq += __shfl_xor(sq, off);
    }
    if (lane == 0) { l0[wave] = s; l1[wave] = sq; }
    __syncthreads();
    if (t == 0) {
      float S  = l0[0] + l0[1] + l0[2] + l0[3];
      float SQ = l1[0] + l1[1] + l1[2] + l1[3];
      float inv = 1.0f / fmaxf(S, 1e-12f);
      stats[2 * b]     = inv;
      stats[2 * b + 1] = SQ * inv * inv;
    }
    return;
  }

  int row = gb;
  const float4* zv = reinterpret_cast<const float4*>(logits + (size_t)row * LL);
  const float* m = mask + (size_t)(row >> 4) * LL;   // K == 16

  __shared__ float cv[CAPL];
  __shared__ int   ci[CAPL];
  __shared__ float cv2[64];
  __shared__ int   ci2[64];
  __shared__ int   nn, n2;
  if (t == 0) { nn = 0; n2 = 0; }
  __syncthreads();

  // ---- single streaming pass: max-accum + speculative filter, NO barrier
  //      between load and use ----
  float mx = -3.0e38f;
#pragma unroll
  for (int j = 0; j < 16; ++j) {
    float4 a = zv[j * 256 + t];
    mx = fmaxf(mx, fmaxf(fmaxf(a.x, a.y), fmaxf(a.z, a.w)));
    int base = (j * 256 + t) * 4;
    float vv[4] = {a.x, a.y, a.z, a.w};
#pragma unroll
    for (int e = 0; e < 4; ++e) {
      if (vv[e] > THR0) {
        int p = atomicAdd(&nn, 1);
        if (p < CAPL) { cv[p] = vv[e]; ci[p] = base + e; }
      }
    }
  }
  for (int off = 32; off; off >>= 1) mx = fmaxf(mx, __shfl_xor(mx, off));
  if (lane == 0) l0[wave] = mx;
  __syncthreads();
  float zmax = fmaxf(fmaxf(l0[0], l0[1]), fmaxf(l0[2], l0[3]));
  float thr = zmax - 1.0f;
  int n = nn;

  if (thr >= THR0 && n <= CAPL) {
    // ======== main path: wave 0 refilters + exact solve ========
    if (wave == 0) {
      for (int i0 = 0; i0 < n; i0 += 64) {
        int i = i0 + lane;
        if (i < n) {
          float x = cv[i];
          if (x > thr) {
            int p = atomicAdd(&n2, 1);
            if (p < 64) { cv2[p] = x; ci2[p] = ci[i]; }
          }
        }
      }
      int nf = n2;   // wave-coherent: own wave's DS ops drained by lgkmcnt
      float a1 = 0.f, a2 = 0.f;
      if (nf <= 64) {
        // exact sorted solve (reference formula) on <=64 true candidates
        float c = (lane < nf) ? cv2[lane] : -3.0e38f;
#pragma unroll
        for (int size = 2; size <= 64; size <<= 1) {
#pragma unroll
          for (int stride = size >> 1; stride > 0; stride >>= 1) {
            float other = __shfl_xor(c, stride);
            bool dirDesc = ((lane & size) == 0);
            bool takeMax = (dirDesc == ((lane & stride) == 0));
            c = takeMax ? fmaxf(c, other) : fminf(c, other);
          }
        }
        float cum = c;
#pragma unroll
        for (int off = 1; off < 64; off <<= 1) {
          float y = __shfl_up(cum, off);
          if (lane >= off) cum += y;
        }
        bool sup = (lane < nf) && (1.0f + (float)(lane + 1) * c > cum);
        unsigned long long bal = __ballot(sup);
        int k = __popcll(bal);            // >= 1 (row max always qualifies)
        float S = sup ? c : 0.f;
        for (int off = 32; off; off >>= 1) S += __shfl_xor(S, off);
        float tau = (S - 1.0f) / (float)k;
        if (lane < nf) {
          float p = fmaxf(cv2[lane] - tau, 0.f);
          if (p > 0.f) { a1 = p * p; a2 = p * m[ci2[lane]]; }
        }
      } else {
        // bisection over the speculative list (valid: support subset, lo>=THR0)
        float lo = thr, hi = zmax;
        int nj = (n + 63) >> 6;
        for (int it = 0; it < 30; ++it) {
          float mid = 0.5f * (lo + hi), s = 0.f;
          for (int j = 0; j < nj; ++j) {
            int i = j * 64 + lane;
            float cc = (i < n) ? cv[i] : -3.0e38f;
            s += fmaxf(cc - mid, 0.f);
          }
          for (int off = 32; off; off >>= 1) s += __shfl_xor(s, off);
          if (s >= 1.0f) lo = mid; else hi = mid;
        }
        float S = 0.f, kc = 0.f;
        for (int j = 0; j < nj; ++j) {
          int i = j * 64 + lane;
          float cc = (i < n) ? cv[i] : -3.0e38f;
          if (cc > lo) { S += cc; kc += 1.f; }
        }
        for (int off = 32; off; off >>= 1) {
          S += __shfl_xor(S, off); kc += __shfl_xor(kc, off);
        }
        float tau = (S - 1.0f) / kc;
        for (int j = 0; j < nj; ++j) {
          int i = j * 64 + lane;
          if (i < n) {
            float p = fmaxf(cv[i] - tau, 0.f);
            if (p > 0.f) { a1 += p * p; a2 += p * m[ci[i]]; }
          }
        }
      }
      for (int off = 32; off; off >>= 1) {
        a1 += __shfl_xor(a1, off); a2 += __shfl_xor(a2, off);
      }
      if (lane == 0) { p1[row] = a1; p2[row] = a2; }
    }
  } else {
    // ======== fallback (P ~ e^-22 per row): full-row bisection ========
    float lo = thr, hi = zmax;
    for (int it = 0; it < 30; ++it) {
      float mid = 0.5f * (lo + hi), s = 0.f;
      for (int j = 0; j < 16; ++j) {
        float4 a = zv[j * 256 + t];
        s += fmaxf(a.x - mid, 0.f) + fmaxf(a.y - mid, 0.f) +
             fmaxf(a.z - mid, 0.f) + fmaxf(a.w - mid, 0.f);
      }
      for (int off = 32; off; off >>= 1) s += __shfl_xor(s, off);
      if (lane == 0) l0[wave] = s;
      __syncthreads();
      float tot = l0[0] + l0[1] + l0[2] + l0[3];
      __syncthreads();
      if (tot >= 1.0f) lo = mid; else hi = mid;
    }
    float S = 0.f, kc = 0.f;
    for (int j = 0; j < 16; ++j) {
      float4 a = zv[j * 256 + t];
      float vv[4] = {a.x, a.y, a.z, a.w};
      for (int e = 0; e < 4; ++e)
        if (vv[e] > lo) { S += vv[e]; kc += 1.f; }
    }
    for (int off = 32; off; off >>= 1) {
      S += __shfl_xor(S, off); kc += __shfl_xor(kc, off);
    }
    if (lane == 0) { l0[wave] = S; l1[wave] = kc; }
    __syncthreads();
    S  = l0[0] + l0[1] + l0[2] + l0[3];
    kc = l1[0] + l1[1] + l1[2] + l1[3];
    float tau = (S - 1.0f) / kc;
    float a1 = 0.f, a2 = 0.f;
    for (int j = 0; j < 16; ++j) {
      float4 a = zv[j * 256 + t];
      int base = (j * 256 + t) * 4;
      float vv[4] = {a.x, a.y, a.z, a.w};
      for (int e = 0; e < 4; ++e) {
        float p = fmaxf(vv[e] - tau, 0.f);
        if (p > 0.f) { a1 += p * p; a2 += p * m[base + e]; }
      }
    }
    for (int off = 32; off; off >>= 1) {
      a1 += __shfl_xor(a1, off); a2 += __shfl_xor(a2, off);
    }
    __syncthreads();
    if (lane == 0) { l0[wave] = a1; l1[wave] = a2; }
    __syncthreads();
    if (t == 0) {
      p1[row] = l0[0] + l0[1] + l0[2] + l0[3];
      p2[row] = l1[0] + l1[1] + l1[2] + l1[3];
    }
  }
}

// ---------------------------------------------------------------------------
// final_reduce: 1 block.  loss = (0.5/NROW) * sum_rows [p1 - 2*inv_s*p2 + q2]
// ---------------------------------------------------------------------------
__global__ __launch_bounds__(256) void final_reduce(
    const float* __restrict__ p1, const float* __restrict__ p2,
    const float* __restrict__ stats, float* __restrict__ out) {
  int t = threadIdx.x;
  float s = 0.f;
#pragma unroll
  for (int j = 0; j < NROW / 256; ++j) {
    int r = j * 256 + t;
    int b = r >> 4;
    s += p1[r] - 2.f * stats[2 * b] * p2[r] + stats[2 * b + 1];
  }
  for (int off = 32; off; off >>= 1) s += __shfl_xor(s, off);
  __shared__ float ls[4];
  if ((t & 63) == 0) ls[t >> 6] = s;
  __syncthreads();
  if (t == 0) out[0] = (ls[0] + ls[1] + ls[2] + ls[3]) * (0.5f / (float)NROW);
}

extern "C" void kernel_launch(void* const* d_in, const int* in_sizes, int n_in,
                              void* d_out, int out_size, void* d_ws, size_t ws_size,
                              hipStream_t stream) {
  const float* logits = (const float*)d_in[0];  // (B,K,L) fp32
  const float* mask   = (const float*)d_in[1];  // (B,L)   fp32
  char* ws = (char*)d_ws;
  float* stats = (float*)ws;             // [0, 512)
  float* p1    = (float*)(ws + 1024);    // [1024, +4096)
  float* p2    = (float*)(ws + 8192);    // [8192, +4096)
  float* out   = (float*)d_out;

  fused_rows<<<NROW + BB, 256, 0, stream>>>(logits, mask, stats, p1, p2);
  final_reduce<<<1, 256, 0, stream>>>(p1, p2, stats, out);
}